// Round 15
// baseline (630.548 us; speedup 1.0000x reference)
//
#include <hip/hip_runtime.h>
#include <hip/hip_bf16.h>
#include <math.h>

#define T_TOKENS 8192
#define HID 1024
#define FFN 2048
#define NEXP 16
#define NPAIR (2*T_TOKENS)
#define TM 128
#define MAXTILES 144

typedef short bf16x8 __attribute__((ext_vector_type(8)));
typedef float f32x4 __attribute__((ext_vector_type(4)));

// ---- workspace layout (bytes) ----
static const size_t HPACK_OFF = 0;                                   // h packed tiles [MAXTILES][32 fb][8192 shorts]
static const size_t HPACK_SZ  = (size_t)MAXTILES * 32 * 16384;       // 75.5 MB
static const size_t GPACK_OFF = HPACK_OFF + HPACK_SZ;                // gup bf16 tiles [16][64 nb][32 kb32][2048 shorts]
static const size_t GPACK_SZ  = (size_t)16 * 64 * 16 * 8192;         // 134 MB
static const size_t DPACK_OFF = GPACK_OFF + GPACK_SZ;                // down bf16 tiles [16][16 nb][64 kb32][2048 shorts]
static const size_t DPACK_SZ  = (size_t)16 * 16 * 32 * 8192;         // 67 MB
static const size_t APACK_OFF = DPACK_OFF + DPACK_SZ;                // gathered A panels [MAXTILES][32 kb32][4096 shorts]
static const size_t APACK_SZ  = (size_t)MAXTILES * 16 * 16384;       // 37.7 MB
static const size_t WTK_OFF   = APACK_OFF + APACK_SZ;
static const size_t ETK_OFF   = WTK_OFF  + (size_t)NPAIR*4;
static const size_t RANK_OFF  = ETK_OFF  + (size_t)NPAIR*4;
static const size_t LIST_OFF  = RANK_OFF + (size_t)NPAIR*4;
static const size_t CNT_OFF   = LIST_OFF + (size_t)NPAIR*4;
static const size_t OFFS_OFF  = CNT_OFF  + 64;
static const size_t TEXP_OFF  = OFFS_OFF + 128;
static const size_t TSEG_OFF  = TEXP_OFF + (size_t)MAXTILES*4;
static const size_t HDR_OFF   = TSEG_OFF + (size_t)MAXTILES*4;
// ydown bf16 [NPAIR][HID] = 33.5 MB, ALIASED onto gpack (gpack dead once k_gateup completes).

__device__ __forceinline__ unsigned short f2bf(float f) {
  union { float f; unsigned u; } v; v.f = f;
  unsigned r = v.u + 0x7fff + ((v.u >> 16) & 1);
  return (unsigned short)(r >> 16);
}

__device__ __forceinline__ float bf2f(unsigned short u) {
  union { unsigned u; float f; } v; v.u = ((unsigned)u) << 16; return v.f;
}

__device__ __forceinline__ bf16x8 pack8(float4 a, float4 b) {
  bf16x8 r;
  r[0]=(short)f2bf(a.x); r[1]=(short)f2bf(a.y); r[2]=(short)f2bf(a.z); r[3]=(short)f2bf(a.w);
  r[4]=(short)f2bf(b.x); r[5]=(short)f2bf(b.y); r[6]=(short)f2bf(b.z); r[7]=(short)f2bf(b.w);
  return r;
}

__device__ __forceinline__ void ld16(const unsigned short* g, unsigned short* l) {
  __builtin_amdgcn_global_load_lds((const __attribute__((address_space(1))) void*)g,
                                   (__attribute__((address_space(3))) void*)l, 16, 0, 0);
}

// m201-discipline sync points (R11-proven):
//  consume side: vmcnt(4) then barrier; overwrite side: lgkmcnt(0)+sched_barrier(0) then barrier.
#define WAITV4 do { asm volatile("s_waitcnt vmcnt(4)" ::: "memory"); } while (0)
#define WAITV0 do { asm volatile("s_waitcnt vmcnt(0)" ::: "memory"); } while (0)
#define WAITL0 do { asm volatile("s_waitcnt lgkmcnt(0)" ::: "memory"); __builtin_amdgcn_sched_barrier(0); } while (0)
#define XBAR   do { __builtin_amdgcn_s_barrier(); __builtin_amdgcn_sched_barrier(0); } while (0)

// ---- weight pack body: fp32 [E][nbcnt*64][kdim] -> bf16 fragment-major tiles ----
__device__ __forceinline__ void pack_body(const float* __restrict__ src, unsigned short* __restrict__ dst,
                                          int e, int nb, int kb, int nbcnt, int kbcnt, int kdim,
                                          unsigned short* tile /*>=4096 shorts*/) {
  int tid = threadIdx.x;
  int n = tid >> 2, ks = (tid & 3) * 16;
  const float* s = src + ((size_t)((e*nbcnt + nb)*64 + n))*kdim + kb*64 + ks;
  float4 f0 = *(const float4*)(s);
  float4 f1 = *(const float4*)(s + 4);
  float4 f2 = *(const float4*)(s + 8);
  float4 f3 = *(const float4*)(s + 12);
  int kkc0 = ks >> 3;
  *(bf16x8*)&tile[(kkc0*64 + n)*8]     = pack8(f0, f1);
  *(bf16x8*)&tile[((kkc0+1)*64 + n)*8] = pack8(f2, f3);
  __syncthreads();
  unsigned short* d = dst + ((size_t)(e*nbcnt + nb)*kbcnt + kb)*4096 + tid*16;
  *(bf16x8*)(d)     = *(const bf16x8*)&tile[tid*16];
  *(bf16x8*)(d + 8) = *(const bf16x8*)&tile[tid*16 + 8];
}

// ---- fused router logits + exact sparsemixer (wave-parallel, lanes 0..15) ----
__global__ __launch_bounds__(256) void k_logroute(const float* __restrict__ x,
                                                  const float* __restrict__ gw,
                                                  float* __restrict__ logits,
                                                  float* __restrict__ wtk, int* __restrict__ etk,
                                                  int* __restrict__ rank, int* __restrict__ counts) {
  int tid = threadIdx.x;
  int wave = tid >> 6, lane = tid & 63;
  int t = blockIdx.x * 4 + wave;
  const float* xp = x + (size_t)t * HID;
  float acc[NEXP];
  #pragma unroll
  for (int e = 0; e < NEXP; e++) acc[e] = 0.f;
  for (int i = lane; i < HID; i += 64) {
    float xv = xp[i];
    #pragma unroll
    for (int e = 0; e < NEXP; e++) acc[e] += xv * gw[e*HID + i];
  }
  float mine = 0.f;
  #pragma unroll
  for (int e = 0; e < NEXP; e++) {
    float v = acc[e];
    #pragma unroll
    for (int o = 32; o > 0; o >>= 1) v += __shfl_xor(v, o, 64);
    if (lane == e) mine = v;
  }
  if (lane < NEXP) logits[(size_t)t*NEXP + lane] = mine;

  // sparsemixer: lane e holds score s_e (lanes >=16 hold -inf, stay in their own xor-group)
  float se = (lane < NEXP) ? mine : -INFINITY;
  // top-1 argmax, first-occurrence tie-break (matches jnp.argmax)
  float mv = se; int mi = lane;
  #pragma unroll
  for (int o = 8; o > 0; o >>= 1) {
    float ov = __shfl_xor(mv, o, 64);
    int   oi = __shfl_xor(mi, o, 64);
    if (ov > mv || (ov == mv && oi < mi)) { mv = ov; mi = oi; }
  }
  float m1 = mv; int i1 = mi;
  float f1 = fmaxf(fabsf(se), m1);
  float t1 = (!((m1 - se) > 0.02f*f1)) ? expf(se - m1) : 0.f;
  #pragma unroll
  for (int o = 8; o > 0; o >>= 1) t1 += __shfl_xor(t1, o, 64);
  // top-2 on masked scores
  float se2 = (lane == i1) ? -INFINITY : se;
  mv = se2; mi = lane;
  #pragma unroll
  for (int o = 8; o > 0; o >>= 1) {
    float ov = __shfl_xor(mv, o, 64);
    int   oi = __shfl_xor(mi, o, 64);
    if (ov > mv || (ov == mv && oi < mi)) { mv = ov; mi = oi; }
  }
  float m2 = mv; int i2 = mi;
  float f2 = fmaxf(fabsf(se), m2);
  float t2 = ((lane != i1) && !((m2 - se) > 0.02f*f2)) ? expf(se - m2) : 0.f;
  #pragma unroll
  for (int o = 8; o > 0; o >>= 1) t2 += __shfl_xor(t2, o, 64);

  if (lane == 0) {
    wtk[t*2]   = 1.f/t1;
    wtk[t*2+1] = 1.f/t2;
    etk[t*2]   = i1;
    etk[t*2+1] = i2;
    rank[t*2]   = atomicAdd(&counts[i1], 1);
    rank[t*2+1] = atomicAdd(&counts[i2], 1);
  }
}

// ---- scan + tile map ----
__global__ void k_scan(const int* __restrict__ counts, int* __restrict__ offsets,
                       int* __restrict__ texp, int* __restrict__ tseg, int* __restrict__ hdr) {
  if (threadIdx.x != 0 || blockIdx.x != 0) return;
  int off = 0, nt = 0;
  for (int e = 0; e < NEXP; e++) {
    offsets[e] = off;
    int c = counts[e];
    int tiles = (c + TM - 1)/TM;
    for (int i = 0; i < tiles; i++) { texp[nt] = e; tseg[nt] = i; nt++; }
    off += c;
  }
  offsets[NEXP] = off;
  hdr[0] = nt;
}

// ---- scatter pair ids into grouped list ----
__global__ __launch_bounds__(256) void k_scatter(const int* __restrict__ etk,
                                                 const int* __restrict__ rank,
                                                 const int* __restrict__ offsets,
                                                 int* __restrict__ list) {
  int p = blockIdx.x*256 + threadIdx.x;
  if (p >= NPAIR) return;
  int e = etk[p];
  list[offsets[e] + rank[p]] = p;
}

// ---- fused prep: pack_gup (16384 blocks) + agather (144 blocks) in one launch ----
__global__ __launch_bounds__(256) void k_prep(const float* __restrict__ gup,
                                              unsigned short* __restrict__ gpack,
                                              const float* __restrict__ x,
                                              const int* __restrict__ list,
                                              const int* __restrict__ counts,
                                              const int* __restrict__ offsets,
                                              const int* __restrict__ texp,
                                              const int* __restrict__ tseg,
                                              const int* __restrict__ hdr,
                                              unsigned short* __restrict__ apack) {
  __shared__ __align__(16) unsigned short tile[4096];
  int bid = blockIdx.x;
  if (bid < 16384) {
    int kb = bid & 15, nb = (bid >> 4) & 63, e = bid >> 10;
    pack_body(gup, gpack, e, nb, kb, 64, 16, HID, tile);
    return;
  }
  int by = bid - 16384;
  if (by >= hdr[0]) return;
  int e = texp[by];
  int m0 = tseg[by]*TM;
  int seg0 = offsets[e];
  int cnt = counts[e];
  int* toks = (int*)tile;
  int tid = threadIdx.x;
  if (tid < TM) toks[tid] = list[seg0 + min(m0 + tid, cnt-1)] >> 1;
  __syncthreads();
  #pragma unroll 4
  for (int it = 0; it < 64; ++it) {
    int flat = it*256 + tid;
    int kb = flat >> 10;
    int i  = flat & 1023;                // entry: kkc*128 + row
    int kkc = i >> 7, row = i & 127;
    const float* s = x + (size_t)toks[row]*HID + kb*64 + kkc*8;
    float4 f0 = *(const float4*)(s);
    float4 f1 = *(const float4*)(s + 4);
    *(bf16x8*)(apack + ((size_t)(by*16 + kb))*8192 + (size_t)i*8) = pack8(f0, f1);
  }
}

// ---- fused: grouped gate_up GEMM (4608 blocks, R11 counted-vmcnt 2-buffer pipeline, BK=32)
//      + pack_down (8192 blocks) role-split streaming under the GEMM ----
__global__ __launch_bounds__(256,4) void k_gateup(const unsigned short* __restrict__ apack,
                                                  const unsigned short* __restrict__ gpack,
                                                  const float* __restrict__ dwn,
                                                  unsigned short* __restrict__ dpack,
                                                  const float* __restrict__ wtk,
                                                  const int* __restrict__ list,
                                                  const int* __restrict__ counts,
                                                  const int* __restrict__ offsets,
                                                  const int* __restrict__ texp,
                                                  const int* __restrict__ tseg,
                                                  const int* __restrict__ hdr,
                                                  unsigned short* __restrict__ hpack) {
  __shared__ __align__(16) unsigned short A_lds[2][4096];   // 2 x 8KB (BK=32)
  __shared__ __align__(16) unsigned short Bg_lds[2][2048];  // 2 x 4KB
  __shared__ __align__(16) unsigned short Bu_lds[2][2048];  // 2 x 4KB  => 32KB total
  int bid = blockIdx.x;
  if (bid >= 4608) {
    int p = bid - 4608;
    pack_body(dwn, dpack, p >> 9, (p >> 5) & 15, p & 31, 16, 32, FFN, &A_lds[0][0]);
    return;
  }
  int fb = bid & 31;    // fb fast: fb%8 -> stable XCD slice (L2-friendly natural order)
  int by = bid >> 5;
  if (by >= hdr[0]) return;
  int e = texp[by];
  int m0 = tseg[by]*TM;
  int seg0 = offsets[e];
  int cnt = counts[e];
  int rows = min(TM, cnt - m0);

  int tid = threadIdx.x;
  int wid = tid >> 6, lane = tid & 63;
  int wr = wid >> 1, wc = wid & 1;
  int c4 = lane >> 4, r16 = lane & 15;

  const unsigned short* gA = apack + (size_t)by * 131072;          // 32 x 4096-short BK=32 panels
  const unsigned short* gG = gpack + ((size_t)(e*64 + fb))      * 65536; // 32 x 2048-short
  const unsigned short* gU = gpack + ((size_t)(e*64 + 32 + fb)) * 65536;

  f32x4 accg[4][2] = {};
  f32x4 accu[4][2] = {};

  auto STAGE = [&](int buf, int kb) {
    #pragma unroll
    for (int s = 0; s < 4; ++s) {
      int i = wid*4 + s;
      if (i < 8) {
        ld16(gA + (size_t)kb*4096 + i*512 + lane*8, &A_lds[buf][i*512]);
      } else if (i < 12) {
        int j = i - 8;
        ld16(gG + (size_t)kb*2048 + j*512 + lane*8, &Bg_lds[buf][j*512]);
      } else {
        int j = i - 12;
        ld16(gU + (size_t)kb*2048 + j*512 + lane*8, &Bu_lds[buf][j*512]);
      }
    }
  };

  auto COMPUTE = [&](int buf) {
    bf16x8 a[4], bg[2], bu[2];
    #pragma unroll
    for (int sm = 0; sm < 4; ++sm)
      a[sm] = *(const bf16x8*)&A_lds[buf][(c4*128 + wr*64 + sm*16 + r16)*8];
    #pragma unroll
    for (int sn = 0; sn < 2; ++sn) {
      bg[sn] = *(const bf16x8*)&Bg_lds[buf][(c4*64 + wc*32 + sn*16 + r16)*8];
      bu[sn] = *(const bf16x8*)&Bu_lds[buf][(c4*64 + wc*32 + sn*16 + r16)*8];
    }
    #pragma unroll
    for (int sm = 0; sm < 4; ++sm)
      #pragma unroll
      for (int sn = 0; sn < 2; ++sn) {
        accg[sm][sn] = __builtin_amdgcn_mfma_f32_16x16x32_bf16(a[sm], bg[sn], accg[sm][sn], 0, 0, 0);
        accu[sm][sn] = __builtin_amdgcn_mfma_f32_16x16x32_bf16(a[sm], bu[sn], accu[sm][sn], 0, 0, 0);
      }
  };

  STAGE(0, 0);
  STAGE(1, 1);                 // 8 loads in flight
  int cur = 0;
  for (int kb = 0; kb < 31; ++kb) {
    WAITV4; XBAR;              // cur's 4 loads landed (all waves); next buf's 4 still fly
    COMPUTE(cur);
    WAITL0; XBAR;              // all waves' ds_reads of cur retired -> cur overwritable
    if (kb < 30) STAGE(cur, kb + 2);
    cur ^= 1;
  }
  WAITV0; XBAR;
  COMPUTE(cur);                // step 31 (cur == 1)
  __syncthreads();             // full drain before scratch reuse

  // epilogue: h = silu(g)*u*w -> packed image in A_lds scratch (16KB contiguous), linear store
  unsigned short* scr = &A_lds[0][0];
  #pragma unroll
  for (int sm = 0; sm < 4; ++sm) {
    #pragma unroll
    for (int j = 0; j < 4; ++j) {
      int row = wr*64 + sm*16 + (lane>>4)*4 + j;
      float w = (row < rows) ? wtk[list[seg0 + m0 + row]] : 0.f;
      #pragma unroll
      for (int sn = 0; sn < 2; ++sn) {
        int col = wc*32 + sn*16 + (lane & 15);
        float g = accg[sm][sn][j];
        float u = accu[sm][sn][j];
        float hv = g / (1.f + __expf(-g)) * u * w;
        scr[((col>>3)*128 + row)*8 + (col&7)] = f2bf(hv);
      }
    }
  }
  __syncthreads();
  unsigned short* dst = hpack + ((size_t)(by*32 + fb))*8192 + tid*32;
  const unsigned short* srcl = scr + tid*32;
  #pragma unroll
  for (int q = 0; q < 4; ++q)
    *(bf16x8*)(dst + q*8) = *(const bf16x8*)(srcl + q*8);
}

// ---- grouped down GEMM: BM=128 x BN=128, R11 counted-vmcnt 2-buffer pipeline (BK=32),
//      bf16 stores to ydown (no atomics) ----
__global__ __launch_bounds__(256,4) void k_down(const unsigned short* __restrict__ hpack,
                                                const unsigned short* __restrict__ dpack,
                                                const int* __restrict__ counts,
                                                const int* __restrict__ texp,
                                                const int* __restrict__ tseg,
                                                const int* __restrict__ offsets,
                                                const int* __restrict__ hdr,
                                                unsigned short* __restrict__ ydown) {
  int nb = blockIdx.x;
  int by = blockIdx.y;
  if (by >= hdr[0]) return;
  int e = texp[by];
  int m0 = tseg[by]*TM;
  int seg0 = offsets[e];
  int cnt = counts[e];
  int rows = min(TM, cnt - m0);

  __shared__ __align__(16) unsigned short A_lds[2][4096];  // 2 x 8KB
  __shared__ __align__(16) unsigned short B_lds[2][4096];  // 2 x 8KB => 32KB

  int tid = threadIdx.x;
  int wid = tid >> 6, lane = tid & 63;
  int wr = wid >> 1, wc = wid & 1;
  int c4 = lane >> 4, r16 = lane & 15;

  const unsigned short* hA = hpack + (size_t)by * 262144;  // 64 x 4096-short BK=32 panels

  f32x4 acc[4][4] = {};

  auto STAGE = [&](int buf, int kb) {
    #pragma unroll
    for (int s = 0; s < 4; ++s) {
      int i = wid*4 + s;
      if (i < 8) {
        ld16(hA + (size_t)kb*4096 + i*512 + lane*8, &A_lds[buf][i*512]);
      } else {
        int i2 = i - 8;
        int p = i2 >> 2, j = i2 & 3;
        ld16(dpack + (((size_t)(e*16 + nb*2 + p))*32 + (kb>>1))*4096 + (kb&1)*2048 + j*512 + lane*8,
             &B_lds[buf][p*2048 + j*512]);
      }
    }
  };

  auto COMPUTE = [&](int buf) {
    bf16x8 a[4], b[4];
    #pragma unroll
    for (int sm = 0; sm < 4; ++sm)
      a[sm] = *(const bf16x8*)&A_lds[buf][(c4*128 + wr*64 + sm*16 + r16)*8];
    #pragma unroll
    for (int sn = 0; sn < 4; ++sn) {
      int col = wc*64 + sn*16 + r16;
      b[sn] = *(const bf16x8*)&B_lds[buf][(col>>6)*2048 + (c4*64 + (col&63))*8];
    }
    #pragma unroll
    for (int sm = 0; sm < 4; ++sm)
      #pragma unroll
      for (int sn = 0; sn < 4; ++sn)
        acc[sm][sn] = __builtin_amdgcn_mfma_f32_16x16x32_bf16(a[sm], b[sn], acc[sm][sn], 0, 0, 0);
  };

  STAGE(0, 0);
  STAGE(1, 1);
  int cur = 0;
  for (int kb = 0; kb < 63; ++kb) {
    WAITV4; XBAR;
    COMPUTE(cur);
    WAITL0; XBAR;
    if (kb < 62) STAGE(cur, kb + 2);
    cur ^= 1;
  }
  WAITV0; XBAR;
  COMPUTE(cur);                // step 63 (cur == 1)

  #pragma unroll
  for (int sm = 0; sm < 4; ++sm) {
    #pragma unroll
    for (int j = 0; j < 4; ++j) {
      int row = wr*64 + sm*16 + (lane>>4)*4 + j;
      if (row < rows) {
        size_t slot = (size_t)(seg0 + m0 + row);
        #pragma unroll
        for (int sn = 0; sn < 4; ++sn) {
          int col = nb*128 + wc*64 + sn*16 + r16;
          ydown[slot*HID + col] = f2bf(acc[sm][sn][j]);
        }
      }
    }
  }
}

// ---- final: out[t] = ydown[slot1(t)] + ydown[slot2(t)]  (bf16 in, fp32 out) ----
__global__ __launch_bounds__(256) void k_final(const unsigned short* __restrict__ ydown,
                                               const int* __restrict__ etk,
                                               const int* __restrict__ rank,
                                               const int* __restrict__ offsets,
                                               float* __restrict__ out) {
  int t = blockIdx.x;
  int c = threadIdx.x;
  int p0 = t*2, p1 = t*2 + 1;
  int s0 = offsets[etk[p0]] + rank[p0];
  int s1 = offsets[etk[p1]] + rank[p1];
  ushort4 a = *(const ushort4*)(ydown + (size_t)s0*HID + c*4);
  ushort4 b = *(const ushort4*)(ydown + (size_t)s1*HID + c*4);
  float4 r;
  r.x = bf2f(a.x) + bf2f(b.x);
  r.y = bf2f(a.y) + bf2f(b.y);
  r.z = bf2f(a.z) + bf2f(b.z);
  r.w = bf2f(a.w) + bf2f(b.w);
  *(float4*)(out + (size_t)t*HID + c*4) = r;
}

extern "C" void kernel_launch(void* const* d_in, const int* in_sizes, int n_in,
                              void* d_out, int out_size, void* d_ws, size_t ws_size,
                              hipStream_t stream) {
  const float* x   = (const float*)d_in[0];
  const float* gw  = (const float*)d_in[1];
  const float* gup = (const float*)d_in[2];
  const float* dwn = (const float*)d_in[3];

  float* out = (float*)d_out;
  float* logits = out + (size_t)T_TOKENS*HID;

  char* ws = (char*)d_ws;
  unsigned short* hpack = (unsigned short*)(ws + HPACK_OFF);
  unsigned short* gpack = (unsigned short*)(ws + GPACK_OFF);
  unsigned short* dpack = (unsigned short*)(ws + DPACK_OFF);
  unsigned short* apack = (unsigned short*)(ws + APACK_OFF);
  unsigned short* ydown = (unsigned short*)(ws + GPACK_OFF);  // alias: gpack dead after k_gateup
  float* wtk   = (float*)(ws + WTK_OFF);
  int* etk     = (int*)(ws + ETK_OFF);
  int* rank    = (int*)(ws + RANK_OFF);
  int* list    = (int*)(ws + LIST_OFF);
  int* counts  = (int*)(ws + CNT_OFF);
  int* offsets = (int*)(ws + OFFS_OFF);
  int* texp    = (int*)(ws + TEXP_OFF);
  int* tseg    = (int*)(ws + TSEG_OFF);
  int* hdr     = (int*)(ws + HDR_OFF);

  hipMemsetAsync(counts, 0, 64, stream);

  // fused routing (logits + sparsemixer + ranks), then scan + scatter
  k_logroute<<<T_TOKENS/4, 256, 0, stream>>>(x, gw, logits, wtk, etk, rank, counts);
  k_scan<<<1, 64, 0, stream>>>(counts, offsets, texp, tseg, hdr);
  k_scatter<<<NPAIR/256, 256, 0, stream>>>(etk, rank, offsets, list);

  // fused pack_gup + agather
  k_prep<<<16384 + MAXTILES, 256, 0, stream>>>(gup, gpack, x, list, counts, offsets, texp, tseg, hdr, apack);

  // fused gate_up GEMM + pack_down (pack streams HBM under the GEMM)
  k_gateup<<<4608 + 8192, 256, 0, stream>>>(apack, gpack, dwn, dpack, wtk, list, counts, offsets,
                                            texp, tseg, hdr, hpack);

  dim3 g4(8, MAXTILES);
  k_down<<<g4, 256, 0, stream>>>(hpack, dpack, counts, texp, tseg, offsets, hdr, ydown);

  k_final<<<T_TOKENS, 256, 0, stream>>>(ydown, etk, rank, offsets, out);
}

// Round 16
// 512.871 us; speedup vs baseline: 1.2294x; 1.2294x over previous
//
#include <hip/hip_runtime.h>
#include <hip/hip_bf16.h>
#include <math.h>

#define T_TOKENS 8192
#define HID 1024
#define FFN 2048
#define NEXP 16
#define NPAIR (2*T_TOKENS)
#define TM 128
#define MAXTILES 144

typedef short bf16x8 __attribute__((ext_vector_type(8)));
typedef float f32x4 __attribute__((ext_vector_type(4)));

// ---- workspace layout (bytes) ----
static const size_t HPACK_OFF = 0;                                   // h packed tiles [MAXTILES][32 fb][8192 shorts]
static const size_t HPACK_SZ  = (size_t)MAXTILES * 32 * 16384;       // 75.5 MB
static const size_t GPACK_OFF = HPACK_OFF + HPACK_SZ;                // gup bf16 tiles [16][64 nb][32 kb32][2048 shorts]
static const size_t GPACK_SZ  = (size_t)16 * 64 * 16 * 8192;         // 134 MB
static const size_t DPACK_OFF = GPACK_OFF + GPACK_SZ;                // down bf16 tiles [16][16 nb][64 kb32][2048 shorts]
static const size_t DPACK_SZ  = (size_t)16 * 16 * 32 * 8192;         // 67 MB
static const size_t APACK_OFF = DPACK_OFF + DPACK_SZ;                // gathered A panels [MAXTILES][32 kb32][4096 shorts]
static const size_t APACK_SZ  = (size_t)MAXTILES * 16 * 16384;       // 37.7 MB
static const size_t WTK_OFF   = APACK_OFF + APACK_SZ;
static const size_t ETK_OFF   = WTK_OFF  + (size_t)NPAIR*4;
static const size_t RANK_OFF  = ETK_OFF  + (size_t)NPAIR*4;
static const size_t LIST_OFF  = RANK_OFF + (size_t)NPAIR*4;
static const size_t CNT_OFF   = LIST_OFF + (size_t)NPAIR*4;
static const size_t OFFS_OFF  = CNT_OFF  + 64;
static const size_t TEXP_OFF  = OFFS_OFF + 128;
static const size_t TSEG_OFF  = TEXP_OFF + (size_t)MAXTILES*4;
static const size_t HDR_OFF   = TSEG_OFF + (size_t)MAXTILES*4;
// ydown bf16 [NPAIR][HID] = 33.5 MB, ALIASED onto gpack (gpack dead once k_gateup completes).

__device__ __forceinline__ unsigned short f2bf(float f) {
  union { float f; unsigned u; } v; v.f = f;
  unsigned r = v.u + 0x7fff + ((v.u >> 16) & 1);
  return (unsigned short)(r >> 16);
}

__device__ __forceinline__ float bf2f(unsigned short u) {
  union { unsigned u; float f; } v; v.u = ((unsigned)u) << 16; return v.f;
}

__device__ __forceinline__ bf16x8 pack8(float4 a, float4 b) {
  bf16x8 r;
  r[0]=(short)f2bf(a.x); r[1]=(short)f2bf(a.y); r[2]=(short)f2bf(a.z); r[3]=(short)f2bf(a.w);
  r[4]=(short)f2bf(b.x); r[5]=(short)f2bf(b.y); r[6]=(short)f2bf(b.z); r[7]=(short)f2bf(b.w);
  return r;
}

__device__ __forceinline__ void ld16(const unsigned short* g, unsigned short* l) {
  __builtin_amdgcn_global_load_lds((const __attribute__((address_space(1))) void*)g,
                                   (__attribute__((address_space(3))) void*)l, 16, 0, 0);
}

// m201-discipline sync points (R11-proven):
//  consume side: vmcnt(4) then barrier; overwrite side: lgkmcnt(0)+sched_barrier(0) then barrier.
#define WAITV4 do { asm volatile("s_waitcnt vmcnt(4)" ::: "memory"); } while (0)
#define WAITV0 do { asm volatile("s_waitcnt vmcnt(0)" ::: "memory"); } while (0)
#define WAITL0 do { asm volatile("s_waitcnt lgkmcnt(0)" ::: "memory"); __builtin_amdgcn_sched_barrier(0); } while (0)
#define XBAR   do { __builtin_amdgcn_s_barrier(); __builtin_amdgcn_sched_barrier(0); } while (0)

// ---- weight pack body: fp32 [E][nbcnt*64][kdim] -> bf16 fragment-major tiles ----
__device__ __forceinline__ void pack_body(const float* __restrict__ src, unsigned short* __restrict__ dst,
                                          int e, int nb, int kb, int nbcnt, int kbcnt, int kdim,
                                          unsigned short* tile /*>=4096 shorts*/) {
  int tid = threadIdx.x;
  int n = tid >> 2, ks = (tid & 3) * 16;
  const float* s = src + ((size_t)((e*nbcnt + nb)*64 + n))*kdim + kb*64 + ks;
  float4 f0 = *(const float4*)(s);
  float4 f1 = *(const float4*)(s + 4);
  float4 f2 = *(const float4*)(s + 8);
  float4 f3 = *(const float4*)(s + 12);
  int kkc0 = ks >> 3;
  *(bf16x8*)&tile[(kkc0*64 + n)*8]     = pack8(f0, f1);
  *(bf16x8*)&tile[((kkc0+1)*64 + n)*8] = pack8(f2, f3);
  __syncthreads();
  unsigned short* d = dst + ((size_t)(e*nbcnt + nb)*kbcnt + kb)*4096 + tid*16;
  *(bf16x8*)(d)     = *(const bf16x8*)&tile[tid*16];
  *(bf16x8*)(d + 8) = *(const bf16x8*)&tile[tid*16 + 8];
}

// ---- router logits (fp32 exact), float4-vectorized: 4 bulk-issued load waves instead of 16 ----
__global__ __launch_bounds__(256) void k_logits(const float* __restrict__ x,
                                                const float* __restrict__ gw,
                                                float* __restrict__ logits) {
  int tid = threadIdx.x;
  int wave = tid >> 6, lane = tid & 63;
  int t = blockIdx.x * 4 + wave;
  const float* xp = x + (size_t)t * HID;
  float acc[NEXP];
  #pragma unroll
  for (int e = 0; e < NEXP; e++) acc[e] = 0.f;
  #pragma unroll
  for (int it = 0; it < 4; ++it) {
    int i = it*256 + lane*4;
    float4 xv = *(const float4*)(xp + i);
    #pragma unroll
    for (int e = 0; e < NEXP; e++) {
      float4 g = *(const float4*)(gw + e*HID + i);
      acc[e] += xv.x*g.x + xv.y*g.y + xv.z*g.z + xv.w*g.w;
    }
  }
  float mine = 0.f;
  #pragma unroll
  for (int e = 0; e < NEXP; e++) {
    float v = acc[e];
    #pragma unroll
    for (int o = 32; o > 0; o >>= 1) v += __shfl_xor(v, o, 64);
    if (lane == e) mine = v;
  }
  if (lane < NEXP) logits[(size_t)t*NEXP + lane] = mine;
}

// ---- exact sparsemixer per token + atomic ranks (R11-proven) ----
__global__ __launch_bounds__(256) void k_route(const float* __restrict__ logits,
                                               float* __restrict__ wtk, int* __restrict__ etk,
                                               int* __restrict__ rank, int* __restrict__ counts) {
  int t = blockIdx.x*256 + threadIdx.x;
  if (t >= T_TOKENS) return;
  float s[NEXP];
  const float* lp = logits + (size_t)t*NEXP;
  #pragma unroll
  for (int e = 0; e < NEXP; e++) s[e] = lp[e];

  float m1 = s[0]; int i1 = 0;
  #pragma unroll
  for (int e = 1; e < NEXP; e++) if (s[e] > m1) { m1 = s[e]; i1 = e; }
  float sum1 = 0.f;
  #pragma unroll
  for (int e = 0; e < NEXP; e++) {
    float f = fmaxf(fabsf(s[e]), m1);
    if (!((m1 - s[e]) > 0.02f*f)) sum1 += expf(s[e]-m1);
  }
  float m2 = -INFINITY; int i2 = 0;
  #pragma unroll
  for (int e = 0; e < NEXP; e++) if (e != i1 && s[e] > m2) { m2 = s[e]; i2 = e; }
  float sum2 = 0.f;
  #pragma unroll
  for (int e = 0; e < NEXP; e++) {
    if (e == i1) continue;
    float f = fmaxf(fabsf(s[e]), m2);
    if (!((m2 - s[e]) > 0.02f*f)) sum2 += expf(s[e]-m2);
  }
  wtk[t*2]   = 1.f/sum1;
  wtk[t*2+1] = 1.f/sum2;
  etk[t*2]   = i1;
  etk[t*2+1] = i2;
  rank[t*2]   = atomicAdd(&counts[i1], 1);
  rank[t*2+1] = atomicAdd(&counts[i2], 1);
}

// ---- scan + tile map ----
__global__ void k_scan(const int* __restrict__ counts, int* __restrict__ offsets,
                       int* __restrict__ texp, int* __restrict__ tseg, int* __restrict__ hdr) {
  if (threadIdx.x != 0 || blockIdx.x != 0) return;
  int off = 0, nt = 0;
  for (int e = 0; e < NEXP; e++) {
    offsets[e] = off;
    int c = counts[e];
    int tiles = (c + TM - 1)/TM;
    for (int i = 0; i < tiles; i++) { texp[nt] = e; tseg[nt] = i; nt++; }
    off += c;
  }
  offsets[NEXP] = off;
  hdr[0] = nt;
}

// ---- scatter pair ids into grouped list ----
__global__ __launch_bounds__(256) void k_scatter(const int* __restrict__ etk,
                                                 const int* __restrict__ rank,
                                                 const int* __restrict__ offsets,
                                                 int* __restrict__ list) {
  int p = blockIdx.x*256 + threadIdx.x;
  if (p >= NPAIR) return;
  int e = etk[p];
  list[offsets[e] + rank[p]] = p;
}

// ---- fused prep: pack_gup (16384 blocks) + agather (144 blocks) in one launch ----
__global__ __launch_bounds__(256) void k_prep(const float* __restrict__ gup,
                                              unsigned short* __restrict__ gpack,
                                              const float* __restrict__ x,
                                              const int* __restrict__ list,
                                              const int* __restrict__ counts,
                                              const int* __restrict__ offsets,
                                              const int* __restrict__ texp,
                                              const int* __restrict__ tseg,
                                              const int* __restrict__ hdr,
                                              unsigned short* __restrict__ apack) {
  __shared__ __align__(16) unsigned short tile[4096];
  int bid = blockIdx.x;
  if (bid < 16384) {
    int kb = bid & 15, nb = (bid >> 4) & 63, e = bid >> 10;
    pack_body(gup, gpack, e, nb, kb, 64, 16, HID, tile);
    return;
  }
  int by = bid - 16384;
  if (by >= hdr[0]) return;
  int e = texp[by];
  int m0 = tseg[by]*TM;
  int seg0 = offsets[e];
  int cnt = counts[e];
  int* toks = (int*)tile;
  int tid = threadIdx.x;
  if (tid < TM) toks[tid] = list[seg0 + min(m0 + tid, cnt-1)] >> 1;
  __syncthreads();
  #pragma unroll 4
  for (int it = 0; it < 64; ++it) {
    int flat = it*256 + tid;
    int kb = flat >> 10;
    int i  = flat & 1023;                // entry: kkc*128 + row
    int kkc = i >> 7, row = i & 127;
    const float* s = x + (size_t)toks[row]*HID + kb*64 + kkc*8;
    float4 f0 = *(const float4*)(s);
    float4 f1 = *(const float4*)(s + 4);
    *(bf16x8*)(apack + ((size_t)(by*16 + kb))*8192 + (size_t)i*8) = pack8(f0, f1);
  }
}

// ---- fused: grouped gate_up GEMM (4608 blocks, R11 counted-vmcnt 2-buffer pipeline, BK=32)
//      + pack_down (8192 blocks) role-split streaming under the GEMM ----
__global__ __launch_bounds__(256,4) void k_gateup(const unsigned short* __restrict__ apack,
                                                  const unsigned short* __restrict__ gpack,
                                                  const float* __restrict__ dwn,
                                                  unsigned short* __restrict__ dpack,
                                                  const float* __restrict__ wtk,
                                                  const int* __restrict__ list,
                                                  const int* __restrict__ counts,
                                                  const int* __restrict__ offsets,
                                                  const int* __restrict__ texp,
                                                  const int* __restrict__ tseg,
                                                  const int* __restrict__ hdr,
                                                  unsigned short* __restrict__ hpack) {
  __shared__ __align__(16) unsigned short A_lds[2][4096];   // 2 x 8KB (BK=32)
  __shared__ __align__(16) unsigned short Bg_lds[2][2048];  // 2 x 4KB
  __shared__ __align__(16) unsigned short Bu_lds[2][2048];  // 2 x 4KB  => 32KB total
  int bid = blockIdx.x;
  if (bid >= 4608) {
    int p = bid - 4608;
    pack_body(dwn, dpack, p >> 9, (p >> 5) & 15, p & 31, 16, 32, FFN, &A_lds[0][0]);
    return;
  }
  int fb = bid & 31;    // fb fast: fb%8 -> stable XCD slice (L2-friendly natural order)
  int by = bid >> 5;
  if (by >= hdr[0]) return;
  int e = texp[by];
  int m0 = tseg[by]*TM;
  int seg0 = offsets[e];
  int cnt = counts[e];
  int rows = min(TM, cnt - m0);

  int tid = threadIdx.x;
  int wid = tid >> 6, lane = tid & 63;
  int wr = wid >> 1, wc = wid & 1;
  int c4 = lane >> 4, r16 = lane & 15;

  const unsigned short* gA = apack + (size_t)by * 131072;          // 32 x 4096-short BK=32 panels
  const unsigned short* gG = gpack + ((size_t)(e*64 + fb))      * 65536; // 32 x 2048-short
  const unsigned short* gU = gpack + ((size_t)(e*64 + 32 + fb)) * 65536;

  f32x4 accg[4][2] = {};
  f32x4 accu[4][2] = {};

  auto STAGE = [&](int buf, int kb) {
    #pragma unroll
    for (int s = 0; s < 4; ++s) {
      int i = wid*4 + s;
      if (i < 8) {
        ld16(gA + (size_t)kb*4096 + i*512 + lane*8, &A_lds[buf][i*512]);
      } else if (i < 12) {
        int j = i - 8;
        ld16(gG + (size_t)kb*2048 + j*512 + lane*8, &Bg_lds[buf][j*512]);
      } else {
        int j = i - 12;
        ld16(gU + (size_t)kb*2048 + j*512 + lane*8, &Bu_lds[buf][j*512]);
      }
    }
  };

  auto COMPUTE = [&](int buf) {
    bf16x8 a[4], bg[2], bu[2];
    #pragma unroll
    for (int sm = 0; sm < 4; ++sm)
      a[sm] = *(const bf16x8*)&A_lds[buf][(c4*128 + wr*64 + sm*16 + r16)*8];
    #pragma unroll
    for (int sn = 0; sn < 2; ++sn) {
      bg[sn] = *(const bf16x8*)&Bg_lds[buf][(c4*64 + wc*32 + sn*16 + r16)*8];
      bu[sn] = *(const bf16x8*)&Bu_lds[buf][(c4*64 + wc*32 + sn*16 + r16)*8];
    }
    #pragma unroll
    for (int sm = 0; sm < 4; ++sm)
      #pragma unroll
      for (int sn = 0; sn < 2; ++sn) {
        accg[sm][sn] = __builtin_amdgcn_mfma_f32_16x16x32_bf16(a[sm], bg[sn], accg[sm][sn], 0, 0, 0);
        accu[sm][sn] = __builtin_amdgcn_mfma_f32_16x16x32_bf16(a[sm], bu[sn], accu[sm][sn], 0, 0, 0);
      }
  };

  STAGE(0, 0);
  STAGE(1, 1);                 // 8 loads in flight
  int cur = 0;
  for (int kb = 0; kb < 31; ++kb) {
    WAITV4; XBAR;              // cur's 4 loads landed (all waves); next buf's 4 still fly
    COMPUTE(cur);
    WAITL0; XBAR;              // all waves' ds_reads of cur retired -> cur overwritable
    if (kb < 30) STAGE(cur, kb + 2);
    cur ^= 1;
  }
  WAITV0; XBAR;
  COMPUTE(cur);                // step 31 (cur == 1)
  __syncthreads();             // full drain before scratch reuse

  // epilogue: h = silu(g)*u*w -> packed image in A_lds scratch (16KB contiguous), linear store
  unsigned short* scr = &A_lds[0][0];
  #pragma unroll
  for (int sm = 0; sm < 4; ++sm) {
    #pragma unroll
    for (int j = 0; j < 4; ++j) {
      int row = wr*64 + sm*16 + (lane>>4)*4 + j;
      float w = (row < rows) ? wtk[list[seg0 + m0 + row]] : 0.f;
      #pragma unroll
      for (int sn = 0; sn < 2; ++sn) {
        int col = wc*32 + sn*16 + (lane & 15);
        float g = accg[sm][sn][j];
        float u = accu[sm][sn][j];
        float hv = g / (1.f + __expf(-g)) * u * w;
        scr[((col>>3)*128 + row)*8 + (col&7)] = f2bf(hv);
      }
    }
  }
  __syncthreads();
  unsigned short* dst = hpack + ((size_t)(by*32 + fb))*8192 + tid*32;
  const unsigned short* srcl = scr + tid*32;
  #pragma unroll
  for (int q = 0; q < 4; ++q)
    *(bf16x8*)(dst + q*8) = *(const bf16x8*)(srcl + q*8);
}

// ---- grouped down GEMM: BM=128 x BN=128, R11 counted-vmcnt 2-buffer pipeline (BK=32),
//      bf16 stores to ydown (no atomics) ----
__global__ __launch_bounds__(256,4) void k_down(const unsigned short* __restrict__ hpack,
                                                const unsigned short* __restrict__ dpack,
                                                const int* __restrict__ counts,
                                                const int* __restrict__ texp,
                                                const int* __restrict__ tseg,
                                                const int* __restrict__ offsets,
                                                const int* __restrict__ hdr,
                                                unsigned short* __restrict__ ydown) {
  int nb = blockIdx.x;
  int by = blockIdx.y;
  if (by >= hdr[0]) return;
  int e = texp[by];
  int m0 = tseg[by]*TM;
  int seg0 = offsets[e];
  int cnt = counts[e];
  int rows = min(TM, cnt - m0);

  __shared__ __align__(16) unsigned short A_lds[2][4096];  // 2 x 8KB
  __shared__ __align__(16) unsigned short B_lds[2][4096];  // 2 x 8KB => 32KB

  int tid = threadIdx.x;
  int wid = tid >> 6, lane = tid & 63;
  int wr = wid >> 1, wc = wid & 1;
  int c4 = lane >> 4, r16 = lane & 15;

  const unsigned short* hA = hpack + (size_t)by * 262144;  // 64 x 4096-short BK=32 panels

  f32x4 acc[4][4] = {};

  auto STAGE = [&](int buf, int kb) {
    #pragma unroll
    for (int s = 0; s < 4; ++s) {
      int i = wid*4 + s;
      if (i < 8) {
        ld16(hA + (size_t)kb*4096 + i*512 + lane*8, &A_lds[buf][i*512]);
      } else {
        int i2 = i - 8;
        int p = i2 >> 2, j = i2 & 3;
        ld16(dpack + (((size_t)(e*16 + nb*2 + p))*32 + (kb>>1))*4096 + (kb&1)*2048 + j*512 + lane*8,
             &B_lds[buf][p*2048 + j*512]);
      }
    }
  };

  auto COMPUTE = [&](int buf) {
    bf16x8 a[4], b[4];
    #pragma unroll
    for (int sm = 0; sm < 4; ++sm)
      a[sm] = *(const bf16x8*)&A_lds[buf][(c4*128 + wr*64 + sm*16 + r16)*8];
    #pragma unroll
    for (int sn = 0; sn < 4; ++sn) {
      int col = wc*64 + sn*16 + r16;
      b[sn] = *(const bf16x8*)&B_lds[buf][(col>>6)*2048 + (c4*64 + (col&63))*8];
    }
    #pragma unroll
    for (int sm = 0; sm < 4; ++sm)
      #pragma unroll
      for (int sn = 0; sn < 4; ++sn)
        acc[sm][sn] = __builtin_amdgcn_mfma_f32_16x16x32_bf16(a[sm], b[sn], acc[sm][sn], 0, 0, 0);
  };

  STAGE(0, 0);
  STAGE(1, 1);
  int cur = 0;
  for (int kb = 0; kb < 63; ++kb) {
    WAITV4; XBAR;
    COMPUTE(cur);
    WAITL0; XBAR;
    if (kb < 62) STAGE(cur, kb + 2);
    cur ^= 1;
  }
  WAITV0; XBAR;
  COMPUTE(cur);                // step 63 (cur == 1)

  #pragma unroll
  for (int sm = 0; sm < 4; ++sm) {
    #pragma unroll
    for (int j = 0; j < 4; ++j) {
      int row = wr*64 + sm*16 + (lane>>4)*4 + j;
      if (row < rows) {
        size_t slot = (size_t)(seg0 + m0 + row);
        #pragma unroll
        for (int sn = 0; sn < 4; ++sn) {
          int col = nb*128 + wc*64 + sn*16 + r16;
          ydown[slot*HID + col] = f2bf(acc[sm][sn][j]);
        }
      }
    }
  }
}

// ---- final: out[t] = ydown[slot1(t)] + ydown[slot2(t)]  (bf16 in, fp32 out) ----
__global__ __launch_bounds__(256) void k_final(const unsigned short* __restrict__ ydown,
                                               const int* __restrict__ etk,
                                               const int* __restrict__ rank,
                                               const int* __restrict__ offsets,
                                               float* __restrict__ out) {
  int t = blockIdx.x;
  int c = threadIdx.x;
  int p0 = t*2, p1 = t*2 + 1;
  int s0 = offsets[etk[p0]] + rank[p0];
  int s1 = offsets[etk[p1]] + rank[p1];
  ushort4 a = *(const ushort4*)(ydown + (size_t)s0*HID + c*4);
  ushort4 b = *(const ushort4*)(ydown + (size_t)s1*HID + c*4);
  float4 r;
  r.x = bf2f(a.x) + bf2f(b.x);
  r.y = bf2f(a.y) + bf2f(b.y);
  r.z = bf2f(a.z) + bf2f(b.z);
  r.w = bf2f(a.w) + bf2f(b.w);
  *(float4*)(out + (size_t)t*HID + c*4) = r;
}

extern "C" void kernel_launch(void* const* d_in, const int* in_sizes, int n_in,
                              void* d_out, int out_size, void* d_ws, size_t ws_size,
                              hipStream_t stream) {
  const float* x   = (const float*)d_in[0];
  const float* gw  = (const float*)d_in[1];
  const float* gup = (const float*)d_in[2];
  const float* dwn = (const float*)d_in[3];

  float* out = (float*)d_out;
  float* logits = out + (size_t)T_TOKENS*HID;

  char* ws = (char*)d_ws;
  unsigned short* hpack = (unsigned short*)(ws + HPACK_OFF);
  unsigned short* gpack = (unsigned short*)(ws + GPACK_OFF);
  unsigned short* dpack = (unsigned short*)(ws + DPACK_OFF);
  unsigned short* apack = (unsigned short*)(ws + APACK_OFF);
  unsigned short* ydown = (unsigned short*)(ws + GPACK_OFF);  // alias: gpack dead after k_gateup
  float* wtk   = (float*)(ws + WTK_OFF);
  int* etk     = (int*)(ws + ETK_OFF);
  int* rank    = (int*)(ws + RANK_OFF);
  int* list    = (int*)(ws + LIST_OFF);
  int* counts  = (int*)(ws + CNT_OFF);
  int* offsets = (int*)(ws + OFFS_OFF);
  int* texp    = (int*)(ws + TEXP_OFF);
  int* tseg    = (int*)(ws + TSEG_OFF);
  int* hdr     = (int*)(ws + HDR_OFF);

  hipMemsetAsync(counts, 0, 64, stream);

  // routing chain (R11 structure, vectorized logits)
  k_logits<<<T_TOKENS/4, 256, 0, stream>>>(x, gw, logits);
  k_route<<<T_TOKENS/256, 256, 0, stream>>>(logits, wtk, etk, rank, counts);
  k_scan<<<1, 64, 0, stream>>>(counts, offsets, texp, tseg, hdr);
  k_scatter<<<NPAIR/256, 256, 0, stream>>>(etk, rank, offsets, list);

  // fused pack_gup + agather
  k_prep<<<16384 + MAXTILES, 256, 0, stream>>>(gup, gpack, x, list, counts, offsets, texp, tseg, hdr, apack);

  // fused gate_up GEMM + pack_down (pack streams HBM under the GEMM)
  k_gateup<<<4608 + 8192, 256, 0, stream>>>(apack, gpack, dwn, dpack, wtk, list, counts, offsets,
                                            texp, tseg, hdr, hpack);

  dim3 g4(8, MAXTILES);
  k_down<<<g4, 256, 0, stream>>>(hpack, dpack, counts, texp, tseg, offsets, hdr, ydown);

  k_final<<<T_TOKENS, 256, 0, stream>>>(ydown, etk, rank, offsets, out);
}

// Round 17
// 457.022 us; speedup vs baseline: 1.3797x; 1.1222x over previous
//
#include <hip/hip_runtime.h>
#include <hip/hip_bf16.h>
#include <math.h>

#define T_TOKENS 8192
#define HID 1024
#define FFN 2048
#define NEXP 16
#define NPAIR (2*T_TOKENS)
#define TM 128
#define MAXTILES 144

typedef short bf16x8 __attribute__((ext_vector_type(8)));
typedef float f32x4 __attribute__((ext_vector_type(4)));

// ---- workspace layout (bytes) ----
static const size_t HPACK_OFF = 0;                                   // h packed tiles [MAXTILES][32 fb][8192 shorts]
static const size_t HPACK_SZ  = (size_t)MAXTILES * 32 * 16384;       // 75.5 MB
static const size_t GPACK_OFF = HPACK_OFF + HPACK_SZ;                // gup bf16 tiles [16][64 nb][32 kb32][2048 shorts]
static const size_t GPACK_SZ  = (size_t)16 * 64 * 16 * 8192;         // 134 MB
static const size_t DPACK_OFF = GPACK_OFF + GPACK_SZ;                // down bf16 tiles [16][16 nb][64 kb32][2048 shorts]
static const size_t DPACK_SZ  = (size_t)16 * 16 * 32 * 8192;         // 67 MB
static const size_t APACK_OFF = DPACK_OFF + DPACK_SZ;                // gathered A panels [MAXTILES][32 kb32][4096 shorts]
static const size_t APACK_SZ  = (size_t)MAXTILES * 16 * 16384;       // 37.7 MB
static const size_t WTK_OFF   = APACK_OFF + APACK_SZ;
static const size_t ETK_OFF   = WTK_OFF  + (size_t)NPAIR*4;
static const size_t RANK_OFF  = ETK_OFF  + (size_t)NPAIR*4;
static const size_t LIST_OFF  = RANK_OFF + (size_t)NPAIR*4;
static const size_t CNT_OFF   = LIST_OFF + (size_t)NPAIR*4;
static const size_t OFFS_OFF  = CNT_OFF  + 64;
static const size_t TEXP_OFF  = OFFS_OFF + 128;
static const size_t TSEG_OFF  = TEXP_OFF + (size_t)MAXTILES*4;
static const size_t HDR_OFF   = TSEG_OFF + (size_t)MAXTILES*4;
// ydown bf16 [NPAIR][HID] = 33.5 MB, ALIASED onto gpack (gpack dead once k_gateup completes).

__device__ __forceinline__ unsigned short f2bf(float f) {
  union { float f; unsigned u; } v; v.f = f;
  unsigned r = v.u + 0x7fff + ((v.u >> 16) & 1);
  return (unsigned short)(r >> 16);
}

__device__ __forceinline__ float bf2f(unsigned short u) {
  union { unsigned u; float f; } v; v.u = ((unsigned)u) << 16; return v.f;
}

__device__ __forceinline__ bf16x8 pack8(float4 a, float4 b) {
  bf16x8 r;
  r[0]=(short)f2bf(a.x); r[1]=(short)f2bf(a.y); r[2]=(short)f2bf(a.z); r[3]=(short)f2bf(a.w);
  r[4]=(short)f2bf(b.x); r[5]=(short)f2bf(b.y); r[6]=(short)f2bf(b.z); r[7]=(short)f2bf(b.w);
  return r;
}

__device__ __forceinline__ void ld16(const unsigned short* g, unsigned short* l) {
  __builtin_amdgcn_global_load_lds((const __attribute__((address_space(1))) void*)g,
                                   (__attribute__((address_space(3))) void*)l, 16, 0, 0);
}

// m201-discipline sync points (R11-proven):
//  consume side: vmcnt(4) then barrier; overwrite side: lgkmcnt(0)+sched_barrier(0) then barrier.
#define WAITV4 do { asm volatile("s_waitcnt vmcnt(4)" ::: "memory"); } while (0)
#define WAITV0 do { asm volatile("s_waitcnt vmcnt(0)" ::: "memory"); } while (0)
#define WAITL0 do { asm volatile("s_waitcnt lgkmcnt(0)" ::: "memory"); __builtin_amdgcn_sched_barrier(0); } while (0)
#define XBAR   do { __builtin_amdgcn_s_barrier(); __builtin_amdgcn_sched_barrier(0); } while (0)

// ---- weight pack body: fp32 [E][nbcnt*64][kdim] -> bf16 fragment-major tiles ----
__device__ __forceinline__ void pack_body(const float* __restrict__ src, unsigned short* __restrict__ dst,
                                          int e, int nb, int kb, int nbcnt, int kbcnt, int kdim,
                                          unsigned short* tile /*>=4096 shorts*/) {
  int tid = threadIdx.x;
  int n = tid >> 2, ks = (tid & 3) * 16;
  const float* s = src + ((size_t)((e*nbcnt + nb)*64 + n))*kdim + kb*64 + ks;
  float4 f0 = *(const float4*)(s);
  float4 f1 = *(const float4*)(s + 4);
  float4 f2 = *(const float4*)(s + 8);
  float4 f3 = *(const float4*)(s + 12);
  int kkc0 = ks >> 3;
  *(bf16x8*)&tile[(kkc0*64 + n)*8]     = pack8(f0, f1);
  *(bf16x8*)&tile[((kkc0+1)*64 + n)*8] = pack8(f2, f3);
  __syncthreads();
  unsigned short* d = dst + ((size_t)(e*nbcnt + nb)*kbcnt + kb)*4096 + tid*16;
  *(bf16x8*)(d)     = *(const bf16x8*)&tile[tid*16];
  *(bf16x8*)(d + 8) = *(const bf16x8*)&tile[tid*16 + 8];
}

// ---- fused: pack_gup (16384 blocks) + router logits (2048 blocks) — independent roles;
//      latency-bound logits hides under pack's BW stream ----
__global__ __launch_bounds__(256) void k_pre(const float* __restrict__ gup,
                                             unsigned short* __restrict__ gpack,
                                             const float* __restrict__ x,
                                             const float* __restrict__ gw,
                                             float* __restrict__ logits) {
  __shared__ __align__(16) unsigned short tile[4096];
  int bid = blockIdx.x;
  if (bid < 16384) {
    int kb = bid & 15, nb = (bid >> 4) & 63, e = bid >> 10;
    pack_body(gup, gpack, e, nb, kb, 64, 16, HID, tile);
    return;
  }
  // logits: 4 tokens per block (one per wave), float4-vectorized
  int lb = bid - 16384;
  int tid = threadIdx.x;
  int wave = tid >> 6, lane = tid & 63;
  int t = lb * 4 + wave;
  const float* xp = x + (size_t)t * HID;
  float acc[NEXP];
  #pragma unroll
  for (int e = 0; e < NEXP; e++) acc[e] = 0.f;
  #pragma unroll
  for (int it = 0; it < 4; ++it) {
    int i = it*256 + lane*4;
    float4 xv = *(const float4*)(xp + i);
    #pragma unroll
    for (int e = 0; e < NEXP; e++) {
      float4 g = *(const float4*)(gw + e*HID + i);
      acc[e] += xv.x*g.x + xv.y*g.y + xv.z*g.z + xv.w*g.w;
    }
  }
  float mine = 0.f;
  #pragma unroll
  for (int e = 0; e < NEXP; e++) {
    float v = acc[e];
    #pragma unroll
    for (int o = 32; o > 0; o >>= 1) v += __shfl_xor(v, o, 64);
    if (lane == e) mine = v;
  }
  if (lane < NEXP) logits[(size_t)t*NEXP + lane] = mine;
}

// ---- exact sparsemixer + two-level atomic ranks (LDS local, one global add per expert/block) ----
__global__ __launch_bounds__(256) void k_route(const float* __restrict__ logits,
                                               float* __restrict__ wtk, int* __restrict__ etk,
                                               int* __restrict__ rank, int* __restrict__ counts) {
  __shared__ int lcnt[NEXP];
  __shared__ int lbase[NEXP];
  int tid = threadIdx.x;
  int t = blockIdx.x*256 + tid;           // grid exactly covers T_TOKENS
  if (tid < NEXP) lcnt[tid] = 0;
  __syncthreads();

  float s[NEXP];
  const float* lp = logits + (size_t)t*NEXP;
  #pragma unroll
  for (int e = 0; e < NEXP; e++) s[e] = lp[e];

  float m1 = s[0]; int i1 = 0;
  #pragma unroll
  for (int e = 1; e < NEXP; e++) if (s[e] > m1) { m1 = s[e]; i1 = e; }
  float sum1 = 0.f;
  #pragma unroll
  for (int e = 0; e < NEXP; e++) {
    float f = fmaxf(fabsf(s[e]), m1);
    if (!((m1 - s[e]) > 0.02f*f)) sum1 += expf(s[e]-m1);
  }
  float m2 = -INFINITY; int i2 = 0;
  #pragma unroll
  for (int e = 0; e < NEXP; e++) if (e != i1 && s[e] > m2) { m2 = s[e]; i2 = e; }
  float sum2 = 0.f;
  #pragma unroll
  for (int e = 0; e < NEXP; e++) {
    if (e == i1) continue;
    float f = fmaxf(fabsf(s[e]), m2);
    if (!((m2 - s[e]) > 0.02f*f)) sum2 += expf(s[e]-m2);
  }
  wtk[t*2]   = 1.f/sum1;
  wtk[t*2+1] = 1.f/sum2;
  etk[t*2]   = i1;
  etk[t*2+1] = i2;
  int r1 = atomicAdd(&lcnt[i1], 1);       // LDS atomics: fast, on-chip
  int r2 = atomicAdd(&lcnt[i2], 1);
  __syncthreads();
  if (tid < NEXP) lbase[tid] = atomicAdd(&counts[tid], lcnt[tid]);  // 16 global atomics/block
  __syncthreads();
  rank[t*2]   = lbase[i1] + r1;
  rank[t*2+1] = lbase[i2] + r2;
}

// ---- scan + tile map ----
__global__ void k_scan(const int* __restrict__ counts, int* __restrict__ offsets,
                       int* __restrict__ texp, int* __restrict__ tseg, int* __restrict__ hdr) {
  if (threadIdx.x != 0 || blockIdx.x != 0) return;
  int off = 0, nt = 0;
  for (int e = 0; e < NEXP; e++) {
    offsets[e] = off;
    int c = counts[e];
    int tiles = (c + TM - 1)/TM;
    for (int i = 0; i < tiles; i++) { texp[nt] = e; tseg[nt] = i; nt++; }
    off += c;
  }
  offsets[NEXP] = off;
  hdr[0] = nt;
}

// ---- scatter pair ids into grouped list ----
__global__ __launch_bounds__(256) void k_scatter(const int* __restrict__ etk,
                                                 const int* __restrict__ rank,
                                                 const int* __restrict__ offsets,
                                                 int* __restrict__ list) {
  int p = blockIdx.x*256 + threadIdx.x;
  if (p >= NPAIR) return;
  int e = etk[p];
  list[offsets[e] + rank[p]] = p;
}

// ---- gather tokens once per tile into packed fragment-major A panels ----
__global__ __launch_bounds__(256) void k_agather(const float* __restrict__ x,
                                                 const int* __restrict__ list,
                                                 const int* __restrict__ counts,
                                                 const int* __restrict__ offsets,
                                                 const int* __restrict__ texp,
                                                 const int* __restrict__ tseg,
                                                 const int* __restrict__ hdr,
                                                 unsigned short* __restrict__ apack) {
  int by = blockIdx.x;
  if (by >= hdr[0]) return;
  int e = texp[by];
  int m0 = tseg[by]*TM;
  int seg0 = offsets[e];
  int cnt = counts[e];
  __shared__ int toks[TM];
  int tid = threadIdx.x;
  if (tid < TM) toks[tid] = list[seg0 + min(m0 + tid, cnt-1)] >> 1;
  __syncthreads();
  #pragma unroll 4
  for (int it = 0; it < 64; ++it) {
    int flat = it*256 + tid;
    int kb = flat >> 10;
    int i  = flat & 1023;                // entry: kkc*128 + row
    int kkc = i >> 7, row = i & 127;
    const float* s = x + (size_t)toks[row]*HID + kb*64 + kkc*8;
    float4 f0 = *(const float4*)(s);
    float4 f1 = *(const float4*)(s + 4);
    *(bf16x8*)(apack + ((size_t)(by*16 + kb))*8192 + (size_t)i*8) = pack8(f0, f1);
  }
}

// ---- fused: grouped gate_up GEMM (4608 blocks, R11 counted-vmcnt 2-buffer pipeline, BK=32)
//      + pack_down (8192 blocks) role-split streaming under the GEMM ----
__global__ __launch_bounds__(256,4) void k_gateup(const unsigned short* __restrict__ apack,
                                                  const unsigned short* __restrict__ gpack,
                                                  const float* __restrict__ dwn,
                                                  unsigned short* __restrict__ dpack,
                                                  const float* __restrict__ wtk,
                                                  const int* __restrict__ list,
                                                  const int* __restrict__ counts,
                                                  const int* __restrict__ offsets,
                                                  const int* __restrict__ texp,
                                                  const int* __restrict__ tseg,
                                                  const int* __restrict__ hdr,
                                                  unsigned short* __restrict__ hpack) {
  __shared__ __align__(16) unsigned short A_lds[2][4096];   // 2 x 8KB (BK=32)
  __shared__ __align__(16) unsigned short Bg_lds[2][2048];  // 2 x 4KB
  __shared__ __align__(16) unsigned short Bu_lds[2][2048];  // 2 x 4KB  => 32KB total
  int bid = blockIdx.x;
  if (bid >= 4608) {
    int p = bid - 4608;
    pack_body(dwn, dpack, p >> 9, (p >> 5) & 15, p & 31, 16, 32, FFN, &A_lds[0][0]);
    return;
  }
  int fb = bid & 31;    // fb fast: fb%8 -> stable XCD slice (L2-friendly natural order)
  int by = bid >> 5;
  if (by >= hdr[0]) return;
  int e = texp[by];
  int m0 = tseg[by]*TM;
  int seg0 = offsets[e];
  int cnt = counts[e];
  int rows = min(TM, cnt - m0);

  int tid = threadIdx.x;
  int wid = tid >> 6, lane = tid & 63;
  int wr = wid >> 1, wc = wid & 1;
  int c4 = lane >> 4, r16 = lane & 15;

  const unsigned short* gA = apack + (size_t)by * 131072;          // 32 x 4096-short BK=32 panels
  const unsigned short* gG = gpack + ((size_t)(e*64 + fb))      * 65536; // 32 x 2048-short
  const unsigned short* gU = gpack + ((size_t)(e*64 + 32 + fb)) * 65536;

  f32x4 accg[4][2] = {};
  f32x4 accu[4][2] = {};

  auto STAGE = [&](int buf, int kb) {
    #pragma unroll
    for (int s = 0; s < 4; ++s) {
      int i = wid*4 + s;
      if (i < 8) {
        ld16(gA + (size_t)kb*4096 + i*512 + lane*8, &A_lds[buf][i*512]);
      } else if (i < 12) {
        int j = i - 8;
        ld16(gG + (size_t)kb*2048 + j*512 + lane*8, &Bg_lds[buf][j*512]);
      } else {
        int j = i - 12;
        ld16(gU + (size_t)kb*2048 + j*512 + lane*8, &Bu_lds[buf][j*512]);
      }
    }
  };

  auto COMPUTE = [&](int buf) {
    bf16x8 a[4], bg[2], bu[2];
    #pragma unroll
    for (int sm = 0; sm < 4; ++sm)
      a[sm] = *(const bf16x8*)&A_lds[buf][(c4*128 + wr*64 + sm*16 + r16)*8];
    #pragma unroll
    for (int sn = 0; sn < 2; ++sn) {
      bg[sn] = *(const bf16x8*)&Bg_lds[buf][(c4*64 + wc*32 + sn*16 + r16)*8];
      bu[sn] = *(const bf16x8*)&Bu_lds[buf][(c4*64 + wc*32 + sn*16 + r16)*8];
    }
    #pragma unroll
    for (int sm = 0; sm < 4; ++sm)
      #pragma unroll
      for (int sn = 0; sn < 2; ++sn) {
        accg[sm][sn] = __builtin_amdgcn_mfma_f32_16x16x32_bf16(a[sm], bg[sn], accg[sm][sn], 0, 0, 0);
        accu[sm][sn] = __builtin_amdgcn_mfma_f32_16x16x32_bf16(a[sm], bu[sn], accu[sm][sn], 0, 0, 0);
      }
  };

  STAGE(0, 0);
  STAGE(1, 1);                 // 8 loads in flight
  int cur = 0;
  for (int kb = 0; kb < 31; ++kb) {
    WAITV4; XBAR;              // cur's 4 loads landed (all waves); next buf's 4 still fly
    COMPUTE(cur);
    WAITL0; XBAR;              // all waves' ds_reads of cur retired -> cur overwritable
    if (kb < 30) STAGE(cur, kb + 2);
    cur ^= 1;
  }
  WAITV0; XBAR;
  COMPUTE(cur);                // step 31 (cur == 1)
  __syncthreads();             // full drain before scratch reuse

  // epilogue: h = silu(g)*u*w -> packed image in A_lds scratch (16KB contiguous), linear store
  unsigned short* scr = &A_lds[0][0];
  #pragma unroll
  for (int sm = 0; sm < 4; ++sm) {
    #pragma unroll
    for (int j = 0; j < 4; ++j) {
      int row = wr*64 + sm*16 + (lane>>4)*4 + j;
      float w = (row < rows) ? wtk[list[seg0 + m0 + row]] : 0.f;
      #pragma unroll
      for (int sn = 0; sn < 2; ++sn) {
        int col = wc*32 + sn*16 + (lane & 15);
        float g = accg[sm][sn][j];
        float u = accu[sm][sn][j];
        float hv = g / (1.f + __expf(-g)) * u * w;
        scr[((col>>3)*128 + row)*8 + (col&7)] = f2bf(hv);
      }
    }
  }
  __syncthreads();
  unsigned short* dst = hpack + ((size_t)(by*32 + fb))*8192 + tid*32;
  const unsigned short* srcl = scr + tid*32;
  #pragma unroll
  for (int q = 0; q < 4; ++q)
    *(bf16x8*)(dst + q*8) = *(const bf16x8*)(srcl + q*8);
}

// ---- grouped down GEMM: BM=128 x BN=128, R11 counted-vmcnt 2-buffer pipeline (BK=32),
//      bf16 stores to ydown (no atomics) ----
__global__ __launch_bounds__(256,4) void k_down(const unsigned short* __restrict__ hpack,
                                                const unsigned short* __restrict__ dpack,
                                                const int* __restrict__ counts,
                                                const int* __restrict__ texp,
                                                const int* __restrict__ tseg,
                                                const int* __restrict__ offsets,
                                                const int* __restrict__ hdr,
                                                unsigned short* __restrict__ ydown) {
  int nb = blockIdx.x;
  int by = blockIdx.y;
  if (by >= hdr[0]) return;
  int e = texp[by];
  int m0 = tseg[by]*TM;
  int seg0 = offsets[e];
  int cnt = counts[e];
  int rows = min(TM, cnt - m0);

  __shared__ __align__(16) unsigned short A_lds[2][4096];  // 2 x 8KB
  __shared__ __align__(16) unsigned short B_lds[2][4096];  // 2 x 8KB => 32KB

  int tid = threadIdx.x;
  int wid = tid >> 6, lane = tid & 63;
  int wr = wid >> 1, wc = wid & 1;
  int c4 = lane >> 4, r16 = lane & 15;

  const unsigned short* hA = hpack + (size_t)by * 262144;  // 64 x 4096-short BK=32 panels

  f32x4 acc[4][4] = {};

  auto STAGE = [&](int buf, int kb) {
    #pragma unroll
    for (int s = 0; s < 4; ++s) {
      int i = wid*4 + s;
      if (i < 8) {
        ld16(hA + (size_t)kb*4096 + i*512 + lane*8, &A_lds[buf][i*512]);
      } else {
        int i2 = i - 8;
        int p = i2 >> 2, j = i2 & 3;
        ld16(dpack + (((size_t)(e*16 + nb*2 + p))*32 + (kb>>1))*4096 + (kb&1)*2048 + j*512 + lane*8,
             &B_lds[buf][p*2048 + j*512]);
      }
    }
  };

  auto COMPUTE = [&](int buf) {
    bf16x8 a[4], b[4];
    #pragma unroll
    for (int sm = 0; sm < 4; ++sm)
      a[sm] = *(const bf16x8*)&A_lds[buf][(c4*128 + wr*64 + sm*16 + r16)*8];
    #pragma unroll
    for (int sn = 0; sn < 4; ++sn) {
      int col = wc*64 + sn*16 + r16;
      b[sn] = *(const bf16x8*)&B_lds[buf][(col>>6)*2048 + (c4*64 + (col&63))*8];
    }
    #pragma unroll
    for (int sm = 0; sm < 4; ++sm)
      #pragma unroll
      for (int sn = 0; sn < 4; ++sn)
        acc[sm][sn] = __builtin_amdgcn_mfma_f32_16x16x32_bf16(a[sm], b[sn], acc[sm][sn], 0, 0, 0);
  };

  STAGE(0, 0);
  STAGE(1, 1);
  int cur = 0;
  for (int kb = 0; kb < 63; ++kb) {
    WAITV4; XBAR;
    COMPUTE(cur);
    WAITL0; XBAR;
    if (kb < 62) STAGE(cur, kb + 2);
    cur ^= 1;
  }
  WAITV0; XBAR;
  COMPUTE(cur);                // step 63 (cur == 1)

  #pragma unroll
  for (int sm = 0; sm < 4; ++sm) {
    #pragma unroll
    for (int j = 0; j < 4; ++j) {
      int row = wr*64 + sm*16 + (lane>>4)*4 + j;
      if (row < rows) {
        size_t slot = (size_t)(seg0 + m0 + row);
        #pragma unroll
        for (int sn = 0; sn < 4; ++sn) {
          int col = nb*128 + wc*64 + sn*16 + r16;
          ydown[slot*HID + col] = f2bf(acc[sm][sn][j]);
        }
      }
    }
  }
}

// ---- final: out[t] = ydown[slot1(t)] + ydown[slot2(t)]  (bf16 in, fp32 out) ----
__global__ __launch_bounds__(256) void k_final(const unsigned short* __restrict__ ydown,
                                               const int* __restrict__ etk,
                                               const int* __restrict__ rank,
                                               const int* __restrict__ offsets,
                                               float* __restrict__ out) {
  int t = blockIdx.x;
  int c = threadIdx.x;
  int p0 = t*2, p1 = t*2 + 1;
  int s0 = offsets[etk[p0]] + rank[p0];
  int s1 = offsets[etk[p1]] + rank[p1];
  ushort4 a = *(const ushort4*)(ydown + (size_t)s0*HID + c*4);
  ushort4 b = *(const ushort4*)(ydown + (size_t)s1*HID + c*4);
  float4 r;
  r.x = bf2f(a.x) + bf2f(b.x);
  r.y = bf2f(a.y) + bf2f(b.y);
  r.z = bf2f(a.z) + bf2f(b.z);
  r.w = bf2f(a.w) + bf2f(b.w);
  *(float4*)(out + (size_t)t*HID + c*4) = r;
}

extern "C" void kernel_launch(void* const* d_in, const int* in_sizes, int n_in,
                              void* d_out, int out_size, void* d_ws, size_t ws_size,
                              hipStream_t stream) {
  const float* x   = (const float*)d_in[0];
  const float* gw  = (const float*)d_in[1];
  const float* gup = (const float*)d_in[2];
  const float* dwn = (const float*)d_in[3];

  float* out = (float*)d_out;
  float* logits = out + (size_t)T_TOKENS*HID;

  char* ws = (char*)d_ws;
  unsigned short* hpack = (unsigned short*)(ws + HPACK_OFF);
  unsigned short* gpack = (unsigned short*)(ws + GPACK_OFF);
  unsigned short* dpack = (unsigned short*)(ws + DPACK_OFF);
  unsigned short* apack = (unsigned short*)(ws + APACK_OFF);
  unsigned short* ydown = (unsigned short*)(ws + GPACK_OFF);  // alias: gpack dead after k_gateup
  float* wtk   = (float*)(ws + WTK_OFF);
  int* etk     = (int*)(ws + ETK_OFF);
  int* rank    = (int*)(ws + RANK_OFF);
  int* list    = (int*)(ws + LIST_OFF);
  int* counts  = (int*)(ws + CNT_OFF);
  int* offsets = (int*)(ws + OFFS_OFF);
  int* texp    = (int*)(ws + TEXP_OFF);
  int* tseg    = (int*)(ws + TSEG_OFF);
  int* hdr     = (int*)(ws + HDR_OFF);

  hipMemsetAsync(counts, 0, 64, stream);

  // pack_gup + logits fused (independent roles; logits latency hides under pack BW)
  k_pre<<<16384 + 2048, 256, 0, stream>>>(gup, gpack, x, gw, logits);

  // routing chain (two-level atomics), then agather
  k_route<<<T_TOKENS/256, 256, 0, stream>>>(logits, wtk, etk, rank, counts);
  k_scan<<<1, 64, 0, stream>>>(counts, offsets, texp, tseg, hdr);
  k_scatter<<<NPAIR/256, 256, 0, stream>>>(etk, rank, offsets, list);
  k_agather<<<MAXTILES, 256, 0, stream>>>(x, list, counts, offsets, texp, tseg, hdr, apack);

  // fused gate_up GEMM + pack_down (pack streams HBM under the GEMM)
  k_gateup<<<4608 + 8192, 256, 0, stream>>>(apack, gpack, dwn, dpack, wtk, list, counts, offsets,
                                            texp, tseg, hdr, hpack);

  dim3 g4(8, MAXTILES);
  k_down<<<g4, 256, 0, stream>>>(hpack, dpack, counts, texp, tseg, offsets, hdr, ydown);

  k_final<<<T_TOKENS, 256, 0, stream>>>(ydown, etk, rank, offsets, out);
}